// Round 6
// baseline (200.803 us; speedup 1.0000x reference)
//
#include <hip/hip_runtime.h>
#include <hip/hip_bf16.h>
#include <math.h>

// Problem constants: N=4, L=1024, D=1024, H=16, HD=64, HIST=128, SCALE=32
// Faithful-bug structure: attention[n,l,h,d] = (sum_q scores[n,h,q,l]) * v[n,l,h,d]
// => only column sums w[n,h,l] of softmax needed.
// Energy trick: q_p . k_p = xq^T (Wq^T Wk / 32) xk, M = Wq^T Wk / 32 (64x64).
// Round 6: k_out 128x64 tiles (512 blocks, 2/CU — m102 grid curve); k_w2
// phase-B loads moved in-loop (bounded VGPR liveness).

using short8 = __attribute__((ext_vector_type(8))) short;
using f32x4  = __attribute__((ext_vector_type(4))) float;

__device__ __forceinline__ unsigned short f2bf(float x) {
    unsigned u = __float_as_uint(x);
    u += 0x7FFFu + ((u >> 16) & 1u);      // round-to-nearest-even
    return (unsigned short)(u >> 16);
}

// ---------------------------------------------------------------------------
// K0 (fused prep), grid 2064:
//  blocks 0..1023   : kbp[nh][l][f] = bf16(keys[n,l,h*64+f]); zero w
//  blocks 1024..2047: wob = bf16(Wo)
//  blocks 2048..2063: Mtb[f][e] = bf16((Wq^T Wk /32)[e][f]); Wvb = bf16(Wv)
// ---------------------------------------------------------------------------
__global__ __launch_bounds__(256) void k_prep(const float* __restrict__ keys,
                                              const float* __restrict__ Wq,
                                              const float* __restrict__ Wk,
                                              const float* __restrict__ Wv,
                                              const float4* __restrict__ Wo4,
                                              unsigned short* __restrict__ kbp,
                                              float* __restrict__ w,
                                              ushort4* __restrict__ wob4,
                                              unsigned short* __restrict__ Mtb,
                                              unsigned short* __restrict__ Wvb) {
    const int b = blockIdx.x, tid = threadIdx.x;
    if (b < 1024) {
        const int tile = b & 15, nh = b >> 4, h = nh & 15, n = nh >> 4;
        const int t0 = tile * 64;
        const float* kbase = keys + ((size_t)(n * 1024 + t0)) * 1024 + h * 64;
        unsigned short* kout = kbp + ((size_t)(nh * 1024 + t0)) * 64;
#pragma unroll
        for (int i = 0; i < 4; ++i) {
            int idx = tid + i * 256;          // 1024 float4s
            int r = idx >> 4, f0 = (idx & 15) * 4;
            float4 kv = *reinterpret_cast<const float4*>(kbase + (size_t)r * 1024 + f0);
            ushort4 ko; ko.x = f2bf(kv.x); ko.y = f2bf(kv.y);
            ko.z = f2bf(kv.z); ko.w = f2bf(kv.w);
            *reinterpret_cast<ushort4*>(kout + (size_t)r * 64 + f0) = ko;
        }
        if (tid < 64) w[b * 64 + tid] = 0.f;
    } else if (b < 2048) {
        int idx = (b - 1024) * 256 + tid;     // 262144 float4s
        float4 v = Wo4[idx];
        ushort4 o; o.x = f2bf(v.x); o.y = f2bf(v.y);
        o.z = f2bf(v.z); o.w = f2bf(v.w);
        wob4[idx] = o;
    } else {
        int idx = (b - 2048) * 256 + tid;     // 4096
        int e = idx >> 6, f = idx & 63;
        float s = 0.f;
#pragma unroll 8
        for (int d = 0; d < 64; ++d) s = fmaf(Wq[d * 64 + e], Wk[d * 64 + f], s);
        Mtb[f * 64 + e] = f2bf(s * (1.0f / 32.0f));   // planar [f][e] for B-frags
        Wvb[idx] = f2bf(Wv[idx]);
    }
}

// ---------------------------------------------------------------------------
// K1: per (nh, 64-row tile):
//  phase A: yq = xq @ M via MFMA (frags direct from global), C->A via LDS.
//  phase B: energy 64x192 MFMA with IN-LOOP B-frag loads (bounded liveness),
//           banded softmax, column sums -> w atomics.
// ---------------------------------------------------------------------------
__global__ __launch_bounds__(256) void k_w2(const float* __restrict__ query,
                                            const unsigned short* __restrict__ kbp,
                                            const unsigned short* __restrict__ Mtb,
                                            float* __restrict__ w) {
    __shared__ unsigned short yqA[64 * 72];   // [r][f] bf16, stride 72
    __shared__ float wloc[192];

    const int tid  = threadIdx.x;
    const int b    = blockIdx.x;          // 1024
    const int tile = b & 15;
    const int nh   = b >> 4;
    const int h    = nh & 15;
    const int n    = nh >> 4;
    const int t0   = tile * 64;

    if (tid < 192) wloc[tid] = 0.f;

    const int wv = tid >> 6, lane = tid & 63;
    const int m = lane & 15, q4 = lane >> 4, ksel = q4 * 8;

    // ---- phase A ----
    {
        const float* qrow = query + ((size_t)(n * 1024 + t0 + wv * 16 + m)) * 1024 + h * 64;
        short8 af[2];
#pragma unroll
        for (int ch = 0; ch < 2; ++ch) {
            float4 x0 = *reinterpret_cast<const float4*>(qrow + ch * 32 + ksel);
            float4 x1 = *reinterpret_cast<const float4*>(qrow + ch * 32 + ksel + 4);
            short8 a;
            a[0] = (short)f2bf(x0.x); a[1] = (short)f2bf(x0.y);
            a[2] = (short)f2bf(x0.z); a[3] = (short)f2bf(x0.w);
            a[4] = (short)f2bf(x1.x); a[5] = (short)f2bf(x1.y);
            a[6] = (short)f2bf(x1.z); a[7] = (short)f2bf(x1.w);
            af[ch] = a;
        }
        f32x4 acc[4];
#pragma unroll
        for (int fc = 0; fc < 4; ++fc) {
            acc[fc] = f32x4{0.f, 0.f, 0.f, 0.f};
#pragma unroll
            for (int ch = 0; ch < 2; ++ch) {
                short8 bf = *reinterpret_cast<const short8*>(
                    Mtb + (size_t)(fc * 16 + m) * 64 + ch * 32 + ksel);
                acc[fc] = __builtin_amdgcn_mfma_f32_16x16x32_bf16(af[ch], bf, acc[fc], 0, 0, 0);
            }
        }
        // C layout (col=m, row=q4*4+reg) -> A-layout LDS tile
#pragma unroll
        for (int fc = 0; fc < 4; ++fc)
#pragma unroll
            for (int r = 0; r < 4; ++r)
                yqA[(wv * 16 + q4 * 4 + r) * 72 + fc * 16 + m] = f2bf(acc[fc][r]);
    }
    __syncthreads();

    // ---- phase B (in-loop B-frag loads: 2 frags live, not 24) ----
    const unsigned short* ya = &yqA[(wv * 16 + m) * 72];
    short8 af0 = *reinterpret_cast<const short8*>(ya + ksel);
    short8 af1 = *reinterpret_cast<const short8*>(ya + 32 + ksel);

    const unsigned short* kb = kbp + (size_t)nh * 1024 * 64;

    f32x4 acc[12];
#pragma unroll
    for (int ni = 0; ni < 12; ++ni) acc[ni] = f32x4{0.f, 0.f, 0.f, 0.f};
#pragma unroll 3
    for (int ni = 0; ni < 12; ++ni) {
        int l = t0 - 127 + ni * 16 + m;
        int lc = min(max(l, 0), 1023);
        const unsigned short* kp = kb + (size_t)lc * 64 + ksel;
        short8 b0 = *reinterpret_cast<const short8*>(kp);
        short8 b1 = *reinterpret_cast<const short8*>(kp + 32);
        acc[ni] = __builtin_amdgcn_mfma_f32_16x16x32_bf16(af0, b0, acc[ni], 0, 0, 0);
        acc[ni] = __builtin_amdgcn_mfma_f32_16x16x32_bf16(af1, b1, acc[ni], 0, 0, 0);
    }

    // banded softmax: col c = ni*16+m, local row = wv*16 + q4*4 + reg
    const int rbase = wv * 16 + q4 * 4;
    float rs[4] = {0.f, 0.f, 0.f, 0.f};
#pragma unroll
    for (int ni = 0; ni < 12; ++ni) {
        const int c = ni * 16 + m;
#pragma unroll
        for (int reg = 0; reg < 4; ++reg) {
            const int rlw = rbase + reg;
            bool valid = (c >= rlw) && (c <= rlw + 127) && (c + t0 >= 127);
            float e = valid ? __expf(acc[ni][reg]) : 0.f;
            acc[ni][reg] = e;
            rs[reg] += e;
        }
    }
#pragma unroll
    for (int reg = 0; reg < 4; ++reg) {
#pragma unroll
        for (int mm = 1; mm < 16; mm <<= 1) rs[reg] += __shfl_xor(rs[reg], mm);
        rs[reg] = 1.0f / rs[reg];         // diagonal always valid -> > 0
    }
#pragma unroll
    for (int ni = 0; ni < 12; ++ni) {
        float cs = acc[ni][0] * rs[0] + acc[ni][1] * rs[1] +
                   acc[ni][2] * rs[2] + acc[ni][3] * rs[3];
        cs += __shfl_xor(cs, 16);
        cs += __shfl_xor(cs, 32);
        if (lane < 16) atomicAdd(&wloc[ni * 16 + m], cs);
    }
    __syncthreads();

    for (int c = tid; c < 192; c += 256) {
        int l = t0 - 127 + c;
        if (l >= 0 && l < 1024)
            atomicAdd(&w[(size_t)nh * 1024 + l], wloc[c]);
    }
}

// ---------------------------------------------------------------------------
// K2: apb[row][d] = bf16( w_scale(row) * sum_e values[row][e] * Wv[d][e] )
// MFMA, frags direct from global. values viewed as (65536, 64) row-major.
// ---------------------------------------------------------------------------
__global__ __launch_bounds__(256) void k_ap2(const float* __restrict__ values,
                                             const unsigned short* __restrict__ Wvb,
                                             const float* __restrict__ w,
                                             unsigned short* __restrict__ apb) {
    const int tid = threadIdx.x;
    const long R0 = (long)blockIdx.x * 64;    // 1024 blocks
    const int wv = tid >> 6, lane = tid & 63;
    const int m = lane & 15, ksel = (lane >> 4) * 8;

    const float* va = values + (R0 + wv * 16 + m) * 64;
    short8 af[2];
#pragma unroll
    for (int ch = 0; ch < 2; ++ch) {
        float4 x0 = *reinterpret_cast<const float4*>(va + ch * 32 + ksel);
        float4 x1 = *reinterpret_cast<const float4*>(va + ch * 32 + ksel + 4);
        short8 a;
        a[0] = (short)f2bf(x0.x); a[1] = (short)f2bf(x0.y);
        a[2] = (short)f2bf(x0.z); a[3] = (short)f2bf(x0.w);
        a[4] = (short)f2bf(x1.x); a[5] = (short)f2bf(x1.y);
        a[6] = (short)f2bf(x1.z); a[7] = (short)f2bf(x1.w);
        af[ch] = a;
    }

    f32x4 acc[4];
#pragma unroll
    for (int dc = 0; dc < 4; ++dc) {
        acc[dc] = f32x4{0.f, 0.f, 0.f, 0.f};
#pragma unroll
        for (int ch = 0; ch < 2; ++ch) {
            short8 bf = *reinterpret_cast<const short8*>(
                Wvb + (size_t)(dc * 16 + m) * 64 + ch * 32 + ksel);
            acc[dc] = __builtin_amdgcn_mfma_f32_16x16x32_bf16(af[ch], bf, acc[dc], 0, 0, 0);
        }
    }

    const long rowb = R0 + wv * 16 + (lane >> 4) * 4;
    float wf[4];
#pragma unroll
    for (int reg = 0; reg < 4; ++reg) {
        long rg = rowb + reg;
        int hh = (int)(rg & 15);
        int ll = (int)((rg >> 4) & 1023);
        int nn = (int)(rg >> 14);
        wf[reg] = w[((size_t)(nn * 16 + hh) << 10) + ll];
    }
#pragma unroll
    for (int dc = 0; dc < 4; ++dc)
#pragma unroll
        for (int reg = 0; reg < 4; ++reg)
            apb[(size_t)(rowb + reg) * 64 + dc * 16 + m] = f2bf(acc[dc][reg] * wf[reg]);
}

// ---------------------------------------------------------------------------
// K3: out = ap (4096x1024 bf16) @ Wo^T (bf16) + bo, f32 out.
// 128x64 tiles -> 512 blocks (2 blocks/CU: inter-block overlap hides the
// vmcnt(0)+barrier drain that stalls the 1-block/CU 128x128 version).
// ---------------------------------------------------------------------------
__global__ __launch_bounds__(256) void k_out_mfma(
    const unsigned short* __restrict__ apb,
    const unsigned short* __restrict__ wob,
    const float* __restrict__ bo,
    float* __restrict__ out) {
    __shared__ unsigned short As[128 * 32];   // 8 KB
    __shared__ unsigned short Bs[64 * 32];    // 4 KB

    const int tid  = threadIdx.x;
    const int wv   = tid >> 6;     // wave 0..3 -> m-rows wv*32..+31
    const int lane = tid & 63;
    const int m    = lane & 15;

    const int bx = blockIdx.x & 15;   // 16 col tiles (64 cols)
    const int by = blockIdx.x >> 4;   // 32 row tiles (128 rows)
    const long arow0 = (long)by * 128;
    const int  bcol0 = bx * 64;

    f32x4 acc[2][4];
#pragma unroll
    for (int mi = 0; mi < 2; ++mi)
#pragma unroll
        for (int ni = 0; ni < 4; ++ni) acc[mi][ni] = f32x4{0.f, 0.f, 0.f, 0.f};

    const int r0s = tid >> 2;         // 0..63
    const int kks = (tid & 3) * 8;

    for (int kt = 0; kt < 32; ++kt) {
        const int k0 = kt * 32;
#pragma unroll
        for (int i = 0; i < 2; ++i) {
            const unsigned short* g =
                apb + (arow0 + i * 64 + r0s) * 1024 + k0 + kks;
            __builtin_amdgcn_global_load_lds(
                (const __attribute__((address_space(1))) unsigned int*)g,
                (__attribute__((address_space(3))) unsigned int*)&As[i * 2048 + wv * 512],
                16, 0, 0);
        }
        {
            const unsigned short* g =
                wob + (size_t)(bcol0 + r0s) * 1024 + k0 + kks;
            __builtin_amdgcn_global_load_lds(
                (const __attribute__((address_space(1))) unsigned int*)g,
                (__attribute__((address_space(3))) unsigned int*)&Bs[wv * 512],
                16, 0, 0);
        }
        __syncthreads();

        const int koff = (lane >> 4) * 8;
        const int rA = wv * 32 + m;
        short8 af[2], bf[4];
#pragma unroll
        for (int mi = 0; mi < 2; ++mi)
            af[mi] = *reinterpret_cast<const short8*>(&As[(rA + mi * 16) * 32 + koff]);
#pragma unroll
        for (int ni = 0; ni < 4; ++ni)
            bf[ni] = *reinterpret_cast<const short8*>(&Bs[(ni * 16 + m) * 32 + koff]);
#pragma unroll
        for (int mi = 0; mi < 2; ++mi)
#pragma unroll
            for (int ni = 0; ni < 4; ++ni)
                acc[mi][ni] = __builtin_amdgcn_mfma_f32_16x16x32_bf16(
                    af[mi], bf[ni], acc[mi][ni], 0, 0, 0);
        __syncthreads();
    }

    const int colb = bcol0 + m;
    const int rowb = (int)arow0 + wv * 32 + (lane >> 4) * 4;
#pragma unroll
    for (int ni = 0; ni < 4; ++ni) {
        const int col = colb + ni * 16;
        const float bias = bo[col];
#pragma unroll
        for (int mi = 0; mi < 2; ++mi) {
            const int row = rowb + mi * 16;
#pragma unroll
            for (int r = 0; r < 4; ++r)
                out[(size_t)(row + r) * 1024 + col] = acc[mi][ni][r] + bias;
        }
    }
}

// ---------------------------------------------------------------------------
extern "C" void kernel_launch(void* const* d_in, const int* in_sizes, int n_in,
                              void* d_out, int out_size, void* d_ws, size_t ws_size,
                              hipStream_t stream) {
    const float* values = (const float*)d_in[0];
    const float* keys   = (const float*)d_in[1];
    const float* query  = (const float*)d_in[2];
    const float* Wv     = (const float*)d_in[4];
    const float* Wk     = (const float*)d_in[5];
    const float* Wq     = (const float*)d_in[6];
    const float* Wo     = (const float*)d_in[7];
    const float* bo     = (const float*)d_in[8];
    float* out = (float*)d_out;

    // workspace layout (~18.3 MB of the 256 MiB ws; no overlays — r3 lesson):
    float* w            = (float*)d_ws;                 // 65536 f32   (256 KB)
    unsigned short* Mtb = (unsigned short*)(w + 65536); // 4096 bf16   (8 KB)
    unsigned short* Wvb = Mtb + 4096;                   // 4096 bf16   (8 KB)
    unsigned short* wob = Wvb + 4096;                   // 1M bf16     (2 MB)
    unsigned short* kbp = wob + 1024 * 1024;            // 4M bf16     (8 MB)
    unsigned short* apb = kbp + 64 * 1024 * 64;         // 4M bf16     (8 MB)

    k_prep<<<2064, 256, 0, stream>>>(keys, Wq, Wk, Wv, (const float4*)Wo,
                                     kbp, w, (ushort4*)wob, Mtb, Wvb);
    k_w2<<<1024, 256, 0, stream>>>(query, kbp, Mtb, w);
    k_ap2<<<1024, 256, 0, stream>>>(values, Wvb, w, apb);
    k_out_mfma<<<512, 256, 0, stream>>>(apb, wob, bo, out);
}

// Round 7
// 162.653 us; speedup vs baseline: 1.2346x; 1.2346x over previous
//
#include <hip/hip_runtime.h>
#include <hip/hip_bf16.h>
#include <math.h>

// Problem constants: N=4, L=1024, D=1024, H=16, HD=64, HIST=128, SCALE=32
// Faithful-bug structure: attention[n,l,h,d] = (sum_q scores[n,h,q,l]) * v[n,l,h,d]
// => only column sums w[n,h,l] of softmax needed.
// Energy trick: E = Xq (Wq^T Wk/32) Xk^T = Xq . kk2^T with kk2 = K.(M^T),
// kk2 precomputed per key row (k_kp) -> k_w2 has no phase A, tiny registers.
// Round 7: r6 regression root cause = acc[] runtime indexing under partial
// unroll -> scratch spill (VGPR_Count 44, WRITE_SIZE 137MB). All register
// arrays now fully unrolled with compile-time indices.

using short8 = __attribute__((ext_vector_type(8))) short;
using f32x4  = __attribute__((ext_vector_type(4))) float;

__device__ __forceinline__ unsigned short f2bf(float x) {
    unsigned u = __float_as_uint(x);
    u += 0x7FFFu + ((u >> 16) & 1u);      // round-to-nearest-even
    return (unsigned short)(u >> 16);
}

// ---------------------------------------------------------------------------
// K0 (prep0), grid 1040:
//  blocks 0..1023 : wob = bf16(Wo); blocks 0..255 additionally zero w
//  blocks 1024..1039: Mrb[e][f] = bf16((Wq^T Wk /32)[e][f]) row-major;
//                     Wvb = bf16(Wv)
// ---------------------------------------------------------------------------
__global__ __launch_bounds__(256) void k_prep0(const float* __restrict__ Wq,
                                               const float* __restrict__ Wk,
                                               const float* __restrict__ Wv,
                                               const float4* __restrict__ Wo4,
                                               float* __restrict__ w,
                                               ushort4* __restrict__ wob4,
                                               unsigned short* __restrict__ Mrb,
                                               unsigned short* __restrict__ Wvb) {
    const int b = blockIdx.x, tid = threadIdx.x;
    if (b < 1024) {
        int idx = b * 256 + tid;              // 262144 float4s
        float4 v = Wo4[idx];
        ushort4 o; o.x = f2bf(v.x); o.y = f2bf(v.y);
        o.z = f2bf(v.z); o.w = f2bf(v.w);
        wob4[idx] = o;
        if (b < 256) w[b * 256 + tid] = 0.f;  // 65536 floats
    } else {
        int idx = (b - 1024) * 256 + tid;     // 4096
        int e = idx >> 6, f = idx & 63;
        float s = 0.f;
#pragma unroll 8
        for (int d = 0; d < 64; ++d) s = fmaf(Wq[d * 64 + e], Wk[d * 64 + f], s);
        Mrb[idx] = f2bf(s * (1.0f / 32.0f));  // row-major [e][f]
        Wvb[idx] = f2bf(Wv[idx]);
    }
}

// ---------------------------------------------------------------------------
// K0b (k_kp): kk2p planar: kk2[nh][l][e] = bf16( sum_f keys[n,l,h*64+f] * M[e,f] )
// keys viewed as (65536,64) rows r=(n*1024+l)*16+h (coalesced A loads);
// output permuted to planar (nh,l) for k_w2's contiguous wave gathers.
// ---------------------------------------------------------------------------
__global__ __launch_bounds__(256) void k_kp(const float* __restrict__ keys,
                                            const unsigned short* __restrict__ Mrb,
                                            unsigned short* __restrict__ kk2p) {
    const int tid = threadIdx.x;
    const long R0 = (long)blockIdx.x * 64;    // 1024 blocks
    const int wv = tid >> 6, lane = tid & 63;
    const int m = lane & 15, ksel = (lane >> 4) * 8;

    const float* ka = keys + (R0 + wv * 16 + m) * 64;
    short8 af[2];
#pragma unroll
    for (int ch = 0; ch < 2; ++ch) {
        float4 x0 = *reinterpret_cast<const float4*>(ka + ch * 32 + ksel);
        float4 x1 = *reinterpret_cast<const float4*>(ka + ch * 32 + ksel + 4);
        short8 a;
        a[0] = (short)f2bf(x0.x); a[1] = (short)f2bf(x0.y);
        a[2] = (short)f2bf(x0.z); a[3] = (short)f2bf(x0.w);
        a[4] = (short)f2bf(x1.x); a[5] = (short)f2bf(x1.y);
        a[6] = (short)f2bf(x1.z); a[7] = (short)f2bf(x1.w);
        af[ch] = a;
    }

    f32x4 acc[4];
#pragma unroll
    for (int fc = 0; fc < 4; ++fc) {
        acc[fc] = f32x4{0.f, 0.f, 0.f, 0.f};
#pragma unroll
        for (int ch = 0; ch < 2; ++ch) {
            short8 bf = *reinterpret_cast<const short8*>(
                Mrb + (size_t)(fc * 16 + m) * 64 + ch * 32 + ksel);
            acc[fc] = __builtin_amdgcn_mfma_f32_16x16x32_bf16(af[ch], bf, acc[fc], 0, 0, 0);
        }
    }

    const long rowb = R0 + wv * 16 + (lane >> 4) * 4;
#pragma unroll
    for (int reg = 0; reg < 4; ++reg) {
        long rg = rowb + reg;
        int hh = (int)(rg & 15);
        int ll = (int)((rg >> 4) & 1023);
        int nn = (int)(rg >> 14);
        unsigned short* orow = kk2p + ((size_t)((nn * 16 + hh) * 1024 + ll)) * 64;
#pragma unroll
        for (int fc = 0; fc < 4; ++fc)
            orow[fc * 16 + m] = f2bf(acc[fc][reg]);
    }
}

// ---------------------------------------------------------------------------
// K1 (k_w2): per (nh, 64-row tile): energy 64x192 via MFMA, A-frags straight
// from query f32, B-frags from planar kk2p (fully unrolled, compile-time
// indices -> no scratch). Banded softmax, column sums -> w atomics.
// ---------------------------------------------------------------------------
__global__ __launch_bounds__(256) void k_w2(const float* __restrict__ query,
                                            const unsigned short* __restrict__ kk2p,
                                            float* __restrict__ w) {
    __shared__ float wloc[192];

    const int tid  = threadIdx.x;
    const int b    = blockIdx.x;          // 1024
    const int tile = b & 15;
    const int nh   = b >> 4;
    const int h    = nh & 15;
    const int n    = nh >> 4;
    const int t0   = tile * 64;

    if (tid < 192) wloc[tid] = 0.f;
    __syncthreads();

    const int wv = tid >> 6, lane = tid & 63;
    const int m = lane & 15, q4 = lane >> 4, ksel = q4 * 8;

    // A-frags: query rows t0 + wv*16 + m (e-components within head h)
    const float* qrow = query + ((size_t)(n * 1024 + t0 + wv * 16 + m)) * 1024 + h * 64;
    short8 af0, af1;
    {
        float4 x0 = *reinterpret_cast<const float4*>(qrow + ksel);
        float4 x1 = *reinterpret_cast<const float4*>(qrow + ksel + 4);
        float4 y0 = *reinterpret_cast<const float4*>(qrow + 32 + ksel);
        float4 y1 = *reinterpret_cast<const float4*>(qrow + 32 + ksel + 4);
        af0[0] = (short)f2bf(x0.x); af0[1] = (short)f2bf(x0.y);
        af0[2] = (short)f2bf(x0.z); af0[3] = (short)f2bf(x0.w);
        af0[4] = (short)f2bf(x1.x); af0[5] = (short)f2bf(x1.y);
        af0[6] = (short)f2bf(x1.z); af0[7] = (short)f2bf(x1.w);
        af1[0] = (short)f2bf(y0.x); af1[1] = (short)f2bf(y0.y);
        af1[2] = (short)f2bf(y0.z); af1[3] = (short)f2bf(y0.w);
        af1[4] = (short)f2bf(y1.x); af1[5] = (short)f2bf(y1.y);
        af1[6] = (short)f2bf(y1.z); af1[7] = (short)f2bf(y1.w);
    }

    const unsigned short* kb = kk2p + (size_t)nh * 1024 * 64;

    f32x4 acc[12];
#pragma unroll
    for (int ni = 0; ni < 12; ++ni) {         // FULL unroll: compile-time idx
        int l = t0 - 127 + ni * 16 + m;
        int lc = min(max(l, 0), 1023);
        const unsigned short* kp = kb + (size_t)lc * 64 + ksel;
        short8 b0 = *reinterpret_cast<const short8*>(kp);
        short8 b1 = *reinterpret_cast<const short8*>(kp + 32);
        f32x4 a = f32x4{0.f, 0.f, 0.f, 0.f};
        a = __builtin_amdgcn_mfma_f32_16x16x32_bf16(af0, b0, a, 0, 0, 0);
        a = __builtin_amdgcn_mfma_f32_16x16x32_bf16(af1, b1, a, 0, 0, 0);
        acc[ni] = a;
    }

    // banded softmax: col c = ni*16+m, local row = wv*16 + q4*4 + reg
    const int rbase = wv * 16 + q4 * 4;
    float rs[4] = {0.f, 0.f, 0.f, 0.f};
#pragma unroll
    for (int ni = 0; ni < 12; ++ni) {
        const int c = ni * 16 + m;
#pragma unroll
        for (int reg = 0; reg < 4; ++reg) {
            const int rlw = rbase + reg;
            bool valid = (c >= rlw) && (c <= rlw + 127) && (c + t0 >= 127);
            float e = valid ? __expf(acc[ni][reg]) : 0.f;
            acc[ni][reg] = e;
            rs[reg] += e;
        }
    }
#pragma unroll
    for (int reg = 0; reg < 4; ++reg) {
#pragma unroll
        for (int mm = 1; mm < 16; mm <<= 1) rs[reg] += __shfl_xor(rs[reg], mm);
        rs[reg] = 1.0f / rs[reg];             // diagonal always valid -> > 0
    }
#pragma unroll
    for (int ni = 0; ni < 12; ++ni) {
        float cs = acc[ni][0] * rs[0] + acc[ni][1] * rs[1] +
                   acc[ni][2] * rs[2] + acc[ni][3] * rs[3];
        cs += __shfl_xor(cs, 16);
        cs += __shfl_xor(cs, 32);
        if (lane < 16) atomicAdd(&wloc[ni * 16 + m], cs);
    }
    __syncthreads();

    for (int c = tid; c < 192; c += 256) {
        int l = t0 - 127 + c;
        if (l >= 0 && l < 1024)
            atomicAdd(&w[(size_t)nh * 1024 + l], wloc[c]);
    }
}

// ---------------------------------------------------------------------------
// K2: apb[row][d] = bf16( w_scale(row) * sum_e values[row][e] * Wv[d][e] )
// MFMA, frags direct from global. values viewed as (65536, 64) row-major.
// ---------------------------------------------------------------------------
__global__ __launch_bounds__(256) void k_ap2(const float* __restrict__ values,
                                             const unsigned short* __restrict__ Wvb,
                                             const float* __restrict__ w,
                                             unsigned short* __restrict__ apb) {
    const int tid = threadIdx.x;
    const long R0 = (long)blockIdx.x * 64;    // 1024 blocks
    const int wv = tid >> 6, lane = tid & 63;
    const int m = lane & 15, ksel = (lane >> 4) * 8;

    const float* va = values + (R0 + wv * 16 + m) * 64;
    short8 af[2];
#pragma unroll
    for (int ch = 0; ch < 2; ++ch) {
        float4 x0 = *reinterpret_cast<const float4*>(va + ch * 32 + ksel);
        float4 x1 = *reinterpret_cast<const float4*>(va + ch * 32 + ksel + 4);
        short8 a;
        a[0] = (short)f2bf(x0.x); a[1] = (short)f2bf(x0.y);
        a[2] = (short)f2bf(x0.z); a[3] = (short)f2bf(x0.w);
        a[4] = (short)f2bf(x1.x); a[5] = (short)f2bf(x1.y);
        a[6] = (short)f2bf(x1.z); a[7] = (short)f2bf(x1.w);
        af[ch] = a;
    }

    f32x4 acc[4];
#pragma unroll
    for (int dc = 0; dc < 4; ++dc) {
        acc[dc] = f32x4{0.f, 0.f, 0.f, 0.f};
#pragma unroll
        for (int ch = 0; ch < 2; ++ch) {
            short8 bf = *reinterpret_cast<const short8*>(
                Wvb + (size_t)(dc * 16 + m) * 64 + ch * 32 + ksel);
            acc[dc] = __builtin_amdgcn_mfma_f32_16x16x32_bf16(af[ch], bf, acc[dc], 0, 0, 0);
        }
    }

    const long rowb = R0 + wv * 16 + (lane >> 4) * 4;
    float wf[4];
#pragma unroll
    for (int reg = 0; reg < 4; ++reg) {
        long rg = rowb + reg;
        int hh = (int)(rg & 15);
        int ll = (int)((rg >> 4) & 1023);
        int nn = (int)(rg >> 14);
        wf[reg] = w[((size_t)(nn * 16 + hh) << 10) + ll];
    }
#pragma unroll
    for (int dc = 0; dc < 4; ++dc)
#pragma unroll
        for (int reg = 0; reg < 4; ++reg)
            apb[(size_t)(rowb + reg) * 64 + dc * 16 + m] = f2bf(acc[dc][reg] * wf[reg]);
}

// ---------------------------------------------------------------------------
// K3: out = ap (4096x1024 bf16) @ Wo^T (bf16) + bo, f32 out.
// 128x64 tiles -> 512 blocks (2 blocks/CU).
// ---------------------------------------------------------------------------
__global__ __launch_bounds__(256) void k_out_mfma(
    const unsigned short* __restrict__ apb,
    const unsigned short* __restrict__ wob,
    const float* __restrict__ bo,
    float* __restrict__ out) {
    __shared__ unsigned short As[128 * 32];   // 8 KB
    __shared__ unsigned short Bs[64 * 32];    // 4 KB

    const int tid  = threadIdx.x;
    const int wv   = tid >> 6;     // wave 0..3 -> m-rows wv*32..+31
    const int lane = tid & 63;
    const int m    = lane & 15;

    const int bx = blockIdx.x & 15;   // 16 col tiles (64 cols)
    const int by = blockIdx.x >> 4;   // 32 row tiles (128 rows)
    const long arow0 = (long)by * 128;
    const int  bcol0 = bx * 64;

    f32x4 acc[2][4];
#pragma unroll
    for (int mi = 0; mi < 2; ++mi)
#pragma unroll
        for (int ni = 0; ni < 4; ++ni) acc[mi][ni] = f32x4{0.f, 0.f, 0.f, 0.f};

    const int r0s = tid >> 2;         // 0..63
    const int kks = (tid & 3) * 8;

    for (int kt = 0; kt < 32; ++kt) {
        const int k0 = kt * 32;
#pragma unroll
        for (int i = 0; i < 2; ++i) {
            const unsigned short* g =
                apb + (arow0 + i * 64 + r0s) * 1024 + k0 + kks;
            __builtin_amdgcn_global_load_lds(
                (const __attribute__((address_space(1))) unsigned int*)g,
                (__attribute__((address_space(3))) unsigned int*)&As[i * 2048 + wv * 512],
                16, 0, 0);
        }
        {
            const unsigned short* g =
                wob + (size_t)(bcol0 + r0s) * 1024 + k0 + kks;
            __builtin_amdgcn_global_load_lds(
                (const __attribute__((address_space(1))) unsigned int*)g,
                (__attribute__((address_space(3))) unsigned int*)&Bs[wv * 512],
                16, 0, 0);
        }
        __syncthreads();

        const int koff = (lane >> 4) * 8;
        const int rA = wv * 32 + m;
        short8 af[2], bf[4];
#pragma unroll
        for (int mi = 0; mi < 2; ++mi)
            af[mi] = *reinterpret_cast<const short8*>(&As[(rA + mi * 16) * 32 + koff]);
#pragma unroll
        for (int ni = 0; ni < 4; ++ni)
            bf[ni] = *reinterpret_cast<const short8*>(&Bs[(ni * 16 + m) * 32 + koff]);
#pragma unroll
        for (int mi = 0; mi < 2; ++mi)
#pragma unroll
            for (int ni = 0; ni < 4; ++ni)
                acc[mi][ni] = __builtin_amdgcn_mfma_f32_16x16x32_bf16(
                    af[mi], bf[ni], acc[mi][ni], 0, 0, 0);
        __syncthreads();
    }

    const int colb = bcol0 + m;
    const int rowb = (int)arow0 + wv * 32 + (lane >> 4) * 4;
#pragma unroll
    for (int ni = 0; ni < 4; ++ni) {
        const int col = colb + ni * 16;
        const float bias = bo[col];
#pragma unroll
        for (int mi = 0; mi < 2; ++mi) {
            const int row = rowb + mi * 16;
#pragma unroll
            for (int r = 0; r < 4; ++r)
                out[(size_t)(row + r) * 1024 + col] = acc[mi][ni][r] + bias;
        }
    }
}

// ---------------------------------------------------------------------------
extern "C" void kernel_launch(void* const* d_in, const int* in_sizes, int n_in,
                              void* d_out, int out_size, void* d_ws, size_t ws_size,
                              hipStream_t stream) {
    const float* values = (const float*)d_in[0];
    const float* keys   = (const float*)d_in[1];
    const float* query  = (const float*)d_in[2];
    const float* Wv     = (const float*)d_in[4];
    const float* Wk     = (const float*)d_in[5];
    const float* Wq     = (const float*)d_in[6];
    const float* Wo     = (const float*)d_in[7];
    const float* bo     = (const float*)d_in[8];
    float* out = (float*)d_out;

    // workspace layout (~18.3 MB of the 256 MiB ws; no overlays — r3 lesson):
    float* w             = (float*)d_ws;                 // 65536 f32   (256 KB)
    unsigned short* Mrb  = (unsigned short*)(w + 65536); // 4096 bf16   (8 KB)
    unsigned short* Wvb  = Mrb + 4096;                   // 4096 bf16   (8 KB)
    unsigned short* wob  = Wvb + 4096;                   // 1M bf16     (2 MB)
    unsigned short* kk2p = wob + 1024 * 1024;            // 4M bf16     (8 MB)
    unsigned short* apb  = kk2p + 64 * 1024 * 64;        // 4M bf16     (8 MB)

    k_prep0<<<1040, 256, 0, stream>>>(Wq, Wk, Wv, (const float4*)Wo,
                                      w, (ushort4*)wob, Mrb, Wvb);
    k_kp<<<1024, 256, 0, stream>>>(keys, Mrb, kk2p);
    k_w2<<<1024, 256, 0, stream>>>(query, kk2p, w);
    k_ap2<<<1024, 256, 0, stream>>>(values, Wvb, w, apb);
    k_out_mfma<<<512, 256, 0, stream>>>(apb, wob, bo, out);
}

// Round 8
// 161.116 us; speedup vs baseline: 1.2463x; 1.0095x over previous
//
#include <hip/hip_runtime.h>
#include <hip/hip_bf16.h>
#include <math.h>

// Problem constants: N=4, L=1024, D=1024, H=16, HD=64, HIST=128, SCALE=32
// Faithful-bug structure: attention[n,l,h,d] = (sum_q scores[n,h,q,l]) * v[n,l,h,d]
// => only column sums w[n,h,l] of softmax needed.
// Energy trick: E = Xq (Wq^T Wk/32) Xk^T = Xq . kk2^T with kk2 = K.(M^T).
// Round 8: XCD-locality swizzles. r2 counter-evidence: k_out FETCH=67.6MB vs
// 10MB of inputs -> A-strip re-fetched per column tile through different
// per-XCD L2s. Same-strip blocks now spaced 32 (==0 mod 8) apart in blockIdx
// so they share one XCD's L2. k_w2: same-nh adjacent tiles co-located.

using short8 = __attribute__((ext_vector_type(8))) short;
using f32x4  = __attribute__((ext_vector_type(4))) float;

__device__ __forceinline__ unsigned short f2bf(float x) {
    unsigned u = __float_as_uint(x);
    u += 0x7FFFu + ((u >> 16) & 1u);      // round-to-nearest-even
    return (unsigned short)(u >> 16);
}

// ---------------------------------------------------------------------------
// K0 (prep0), grid 1040:
//  blocks 0..1023 : wob = bf16(Wo); blocks 0..255 additionally zero w
//  blocks 1024..1039: Mrb[e][f] = bf16((Wq^T Wk /32)[e][f]); Wvb = bf16(Wv)
// ---------------------------------------------------------------------------
__global__ __launch_bounds__(256) void k_prep0(const float* __restrict__ Wq,
                                               const float* __restrict__ Wk,
                                               const float* __restrict__ Wv,
                                               const float4* __restrict__ Wo4,
                                               float* __restrict__ w,
                                               ushort4* __restrict__ wob4,
                                               unsigned short* __restrict__ Mrb,
                                               unsigned short* __restrict__ Wvb) {
    const int b = blockIdx.x, tid = threadIdx.x;
    if (b < 1024) {
        int idx = b * 256 + tid;              // 262144 float4s
        float4 v = Wo4[idx];
        ushort4 o; o.x = f2bf(v.x); o.y = f2bf(v.y);
        o.z = f2bf(v.z); o.w = f2bf(v.w);
        wob4[idx] = o;
        if (b < 256) w[b * 256 + tid] = 0.f;  // 65536 floats
    } else {
        int idx = (b - 1024) * 256 + tid;     // 4096
        int e = idx >> 6, f = idx & 63;
        float s = 0.f;
#pragma unroll 8
        for (int d = 0; d < 64; ++d) s = fmaf(Wq[d * 64 + e], Wk[d * 64 + f], s);
        Mrb[idx] = f2bf(s * (1.0f / 32.0f));  // row-major [e][f]
        Wvb[idx] = f2bf(Wv[idx]);
    }
}

// ---------------------------------------------------------------------------
// K0b (k_kp): kk2p planar: kk2[nh][l][e] = bf16( sum_f keys[n,l,h*64+f] * M[e,f] )
// ---------------------------------------------------------------------------
__global__ __launch_bounds__(256) void k_kp(const float* __restrict__ keys,
                                            const unsigned short* __restrict__ Mrb,
                                            unsigned short* __restrict__ kk2p) {
    const int tid = threadIdx.x;
    const long R0 = (long)blockIdx.x * 64;    // 1024 blocks
    const int wv = tid >> 6, lane = tid & 63;
    const int m = lane & 15, ksel = (lane >> 4) * 8;

    const float* ka = keys + (R0 + wv * 16 + m) * 64;
    short8 af[2];
#pragma unroll
    for (int ch = 0; ch < 2; ++ch) {
        float4 x0 = *reinterpret_cast<const float4*>(ka + ch * 32 + ksel);
        float4 x1 = *reinterpret_cast<const float4*>(ka + ch * 32 + ksel + 4);
        short8 a;
        a[0] = (short)f2bf(x0.x); a[1] = (short)f2bf(x0.y);
        a[2] = (short)f2bf(x0.z); a[3] = (short)f2bf(x0.w);
        a[4] = (short)f2bf(x1.x); a[5] = (short)f2bf(x1.y);
        a[6] = (short)f2bf(x1.z); a[7] = (short)f2bf(x1.w);
        af[ch] = a;
    }

    f32x4 acc[4];
#pragma unroll
    for (int fc = 0; fc < 4; ++fc) {
        acc[fc] = f32x4{0.f, 0.f, 0.f, 0.f};
#pragma unroll
        for (int ch = 0; ch < 2; ++ch) {
            short8 bf = *reinterpret_cast<const short8*>(
                Mrb + (size_t)(fc * 16 + m) * 64 + ch * 32 + ksel);
            acc[fc] = __builtin_amdgcn_mfma_f32_16x16x32_bf16(af[ch], bf, acc[fc], 0, 0, 0);
        }
    }

    const long rowb = R0 + wv * 16 + (lane >> 4) * 4;
#pragma unroll
    for (int reg = 0; reg < 4; ++reg) {
        long rg = rowb + reg;
        int hh = (int)(rg & 15);
        int ll = (int)((rg >> 4) & 1023);
        int nn = (int)(rg >> 14);
        unsigned short* orow = kk2p + ((size_t)((nn * 16 + hh) * 1024 + ll)) * 64;
#pragma unroll
        for (int fc = 0; fc < 4; ++fc)
            orow[fc * 16 + m] = f2bf(acc[fc][reg]);
    }
}

// ---------------------------------------------------------------------------
// K1 (k_w2): per (nh, 64-row tile): energy 64x192 via MFMA, banded softmax,
// column sums -> w atomics. Swizzled decode: same-nh adjacent tiles spaced 64
// apart in blockIdx (same XCD residue) -> kk2p band overlap stays in one L2.
// ---------------------------------------------------------------------------
__global__ __launch_bounds__(256) void k_w2(const float* __restrict__ query,
                                            const unsigned short* __restrict__ kk2p,
                                            float* __restrict__ w) {
    __shared__ float wloc[192];

    const int tid  = threadIdx.x;
    const int b    = blockIdx.x;          // 1024
    const int nh   = b & 63;              // swizzle: nh fast, tile slow
    const int tile = b >> 6;
    const int h    = nh & 15;
    const int n    = nh >> 4;
    const int t0   = tile * 64;

    if (tid < 192) wloc[tid] = 0.f;
    __syncthreads();

    const int wv = tid >> 6, lane = tid & 63;
    const int m = lane & 15, q4 = lane >> 4, ksel = q4 * 8;

    // A-frags: query rows t0 + wv*16 + m (e-components within head h)
    const float* qrow = query + ((size_t)(n * 1024 + t0 + wv * 16 + m)) * 1024 + h * 64;
    short8 af0, af1;
    {
        float4 x0 = *reinterpret_cast<const float4*>(qrow + ksel);
        float4 x1 = *reinterpret_cast<const float4*>(qrow + ksel + 4);
        float4 y0 = *reinterpret_cast<const float4*>(qrow + 32 + ksel);
        float4 y1 = *reinterpret_cast<const float4*>(qrow + 32 + ksel + 4);
        af0[0] = (short)f2bf(x0.x); af0[1] = (short)f2bf(x0.y);
        af0[2] = (short)f2bf(x0.z); af0[3] = (short)f2bf(x0.w);
        af0[4] = (short)f2bf(x1.x); af0[5] = (short)f2bf(x1.y);
        af0[6] = (short)f2bf(x1.z); af0[7] = (short)f2bf(x1.w);
        af1[0] = (short)f2bf(y0.x); af1[1] = (short)f2bf(y0.y);
        af1[2] = (short)f2bf(y0.z); af1[3] = (short)f2bf(y0.w);
        af1[4] = (short)f2bf(y1.x); af1[5] = (short)f2bf(y1.y);
        af1[6] = (short)f2bf(y1.z); af1[7] = (short)f2bf(y1.w);
    }

    const unsigned short* kb = kk2p + (size_t)nh * 1024 * 64;

    f32x4 acc[12];
#pragma unroll
    for (int ni = 0; ni < 12; ++ni) {         // FULL unroll: compile-time idx
        int l = t0 - 127 + ni * 16 + m;
        int lc = min(max(l, 0), 1023);
        const unsigned short* kp = kb + (size_t)lc * 64 + ksel;
        short8 b0 = *reinterpret_cast<const short8*>(kp);
        short8 b1 = *reinterpret_cast<const short8*>(kp + 32);
        f32x4 a = f32x4{0.f, 0.f, 0.f, 0.f};
        a = __builtin_amdgcn_mfma_f32_16x16x32_bf16(af0, b0, a, 0, 0, 0);
        a = __builtin_amdgcn_mfma_f32_16x16x32_bf16(af1, b1, a, 0, 0, 0);
        acc[ni] = a;
    }

    // banded softmax: col c = ni*16+m, local row = wv*16 + q4*4 + reg
    const int rbase = wv * 16 + q4 * 4;
    float rs[4] = {0.f, 0.f, 0.f, 0.f};
#pragma unroll
    for (int ni = 0; ni < 12; ++ni) {
        const int c = ni * 16 + m;
#pragma unroll
        for (int reg = 0; reg < 4; ++reg) {
            const int rlw = rbase + reg;
            bool valid = (c >= rlw) && (c <= rlw + 127) && (c + t0 >= 127);
            float e = valid ? __expf(acc[ni][reg]) : 0.f;
            acc[ni][reg] = e;
            rs[reg] += e;
        }
    }
#pragma unroll
    for (int reg = 0; reg < 4; ++reg) {
#pragma unroll
        for (int mm = 1; mm < 16; mm <<= 1) rs[reg] += __shfl_xor(rs[reg], mm);
        rs[reg] = 1.0f / rs[reg];             // diagonal always valid -> > 0
    }
#pragma unroll
    for (int ni = 0; ni < 12; ++ni) {
        float cs = acc[ni][0] * rs[0] + acc[ni][1] * rs[1] +
                   acc[ni][2] * rs[2] + acc[ni][3] * rs[3];
        cs += __shfl_xor(cs, 16);
        cs += __shfl_xor(cs, 32);
        if (lane < 16) atomicAdd(&wloc[ni * 16 + m], cs);
    }
    __syncthreads();

    for (int c = tid; c < 192; c += 256) {
        int l = t0 - 127 + c;
        if (l >= 0 && l < 1024)
            atomicAdd(&w[(size_t)nh * 1024 + l], wloc[c]);
    }
}

// ---------------------------------------------------------------------------
// K2: apb[row][d] = bf16( w_scale(row) * sum_e values[row][e] * Wv[d][e] )
// ---------------------------------------------------------------------------
__global__ __launch_bounds__(256) void k_ap2(const float* __restrict__ values,
                                             const unsigned short* __restrict__ Wvb,
                                             const float* __restrict__ w,
                                             unsigned short* __restrict__ apb) {
    const int tid = threadIdx.x;
    const long R0 = (long)blockIdx.x * 64;    // 1024 blocks
    const int wv = tid >> 6, lane = tid & 63;
    const int m = lane & 15, ksel = (lane >> 4) * 8;

    const float* va = values + (R0 + wv * 16 + m) * 64;
    short8 af[2];
#pragma unroll
    for (int ch = 0; ch < 2; ++ch) {
        float4 x0 = *reinterpret_cast<const float4*>(va + ch * 32 + ksel);
        float4 x1 = *reinterpret_cast<const float4*>(va + ch * 32 + ksel + 4);
        short8 a;
        a[0] = (short)f2bf(x0.x); a[1] = (short)f2bf(x0.y);
        a[2] = (short)f2bf(x0.z); a[3] = (short)f2bf(x0.w);
        a[4] = (short)f2bf(x1.x); a[5] = (short)f2bf(x1.y);
        a[6] = (short)f2bf(x1.z); a[7] = (short)f2bf(x1.w);
        af[ch] = a;
    }

    f32x4 acc[4];
#pragma unroll
    for (int dc = 0; dc < 4; ++dc) {
        acc[dc] = f32x4{0.f, 0.f, 0.f, 0.f};
#pragma unroll
        for (int ch = 0; ch < 2; ++ch) {
            short8 bf = *reinterpret_cast<const short8*>(
                Wvb + (size_t)(dc * 16 + m) * 64 + ch * 32 + ksel);
            acc[dc] = __builtin_amdgcn_mfma_f32_16x16x32_bf16(af[ch], bf, acc[dc], 0, 0, 0);
        }
    }

    const long rowb = R0 + wv * 16 + (lane >> 4) * 4;
    float wf[4];
#pragma unroll
    for (int reg = 0; reg < 4; ++reg) {
        long rg = rowb + reg;
        int hh = (int)(rg & 15);
        int ll = (int)((rg >> 4) & 1023);
        int nn = (int)(rg >> 14);
        wf[reg] = w[((size_t)(nn * 16 + hh) << 10) + ll];
    }
#pragma unroll
    for (int dc = 0; dc < 4; ++dc)
#pragma unroll
        for (int reg = 0; reg < 4; ++reg)
            apb[(size_t)(rowb + reg) * 64 + dc * 16 + m] = f2bf(acc[dc][reg] * wf[reg]);
}

// ---------------------------------------------------------------------------
// K3: out = ap (4096x1024 bf16) @ Wo^T (bf16) + bo, f32 out.
// 128x64 tiles, 512 blocks, SWIZZLED: by = blk&31 (strip), bx = blk>>5.
// The 16 blocks sharing an A-strip are spaced 32 apart (== same XCD residue
// mod 8) -> strip fetched ~once per XCD L2 instead of per block.
// ---------------------------------------------------------------------------
__global__ __launch_bounds__(256) void k_out_mfma(
    const unsigned short* __restrict__ apb,
    const unsigned short* __restrict__ wob,
    const float* __restrict__ bo,
    float* __restrict__ out) {
    __shared__ unsigned short As[128 * 32];   // 8 KB
    __shared__ unsigned short Bs[64 * 32];    // 4 KB

    const int tid  = threadIdx.x;
    const int wv   = tid >> 6;     // wave 0..3 -> m-rows wv*32..+31
    const int lane = tid & 63;
    const int m    = lane & 15;

    const int by = blockIdx.x & 31;   // row strip (swizzle: strip fast)
    const int bx = blockIdx.x >> 5;   // 16 col tiles (64 cols)
    const long arow0 = (long)by * 128;
    const int  bcol0 = bx * 64;

    f32x4 acc[2][4];
#pragma unroll
    for (int mi = 0; mi < 2; ++mi)
#pragma unroll
        for (int ni = 0; ni < 4; ++ni) acc[mi][ni] = f32x4{0.f, 0.f, 0.f, 0.f};

    const int r0s = tid >> 2;         // 0..63
    const int kks = (tid & 3) * 8;

    for (int kt = 0; kt < 32; ++kt) {
        const int k0 = kt * 32;
#pragma unroll
        for (int i = 0; i < 2; ++i) {
            const unsigned short* g =
                apb + (arow0 + i * 64 + r0s) * 1024 + k0 + kks;
            __builtin_amdgcn_global_load_lds(
                (const __attribute__((address_space(1))) unsigned int*)g,
                (__attribute__((address_space(3))) unsigned int*)&As[i * 2048 + wv * 512],
                16, 0, 0);
        }
        {
            const unsigned short* g =
                wob + (size_t)(bcol0 + r0s) * 1024 + k0 + kks;
            __builtin_amdgcn_global_load_lds(
                (const __attribute__((address_space(1))) unsigned int*)g,
                (__attribute__((address_space(3))) unsigned int*)&Bs[wv * 512],
                16, 0, 0);
        }
        __syncthreads();

        const int koff = (lane >> 4) * 8;
        const int rA = wv * 32 + m;
        short8 af[2], bf[4];
#pragma unroll
        for (int mi = 0; mi < 2; ++mi)
            af[mi] = *reinterpret_cast<const short8*>(&As[(rA + mi * 16) * 32 + koff]);
#pragma unroll
        for (int ni = 0; ni < 4; ++ni)
            bf[ni] = *reinterpret_cast<const short8*>(&Bs[(ni * 16 + m) * 32 + koff]);
#pragma unroll
        for (int mi = 0; mi < 2; ++mi)
#pragma unroll
            for (int ni = 0; ni < 4; ++ni)
                acc[mi][ni] = __builtin_amdgcn_mfma_f32_16x16x32_bf16(
                    af[mi], bf[ni], acc[mi][ni], 0, 0, 0);
        __syncthreads();
    }

    const int colb = bcol0 + m;
    const int rowb = (int)arow0 + wv * 32 + (lane >> 4) * 4;
#pragma unroll
    for (int ni = 0; ni < 4; ++ni) {
        const int col = colb + ni * 16;
        const float bias = bo[col];
#pragma unroll
        for (int mi = 0; mi < 2; ++mi) {
            const int row = rowb + mi * 16;
#pragma unroll
            for (int r = 0; r < 4; ++r)
                out[(size_t)(row + r) * 1024 + col] = acc[mi][ni][r] + bias;
        }
    }
}

// ---------------------------------------------------------------------------
extern "C" void kernel_launch(void* const* d_in, const int* in_sizes, int n_in,
                              void* d_out, int out_size, void* d_ws, size_t ws_size,
                              hipStream_t stream) {
    const float* values = (const float*)d_in[0];
    const float* keys   = (const float*)d_in[1];
    const float* query  = (const float*)d_in[2];
    const float* Wv     = (const float*)d_in[4];
    const float* Wk     = (const float*)d_in[5];
    const float* Wq     = (const float*)d_in[6];
    const float* Wo     = (const float*)d_in[7];
    const float* bo     = (const float*)d_in[8];
    float* out = (float*)d_out;

    // workspace layout (~18.3 MB of the 256 MiB ws; no overlays — r3 lesson):
    float* w             = (float*)d_ws;                 // 65536 f32   (256 KB)
    unsigned short* Mrb  = (unsigned short*)(w + 65536); // 4096 bf16   (8 KB)
    unsigned short* Wvb  = Mrb + 4096;                   // 4096 bf16   (8 KB)
    unsigned short* wob  = Wvb + 4096;                   // 1M bf16     (2 MB)
    unsigned short* kk2p = wob + 1024 * 1024;            // 4M bf16     (8 MB)
    unsigned short* apb  = kk2p + 64 * 1024 * 64;        // 4M bf16     (8 MB)

    k_prep0<<<1040, 256, 0, stream>>>(Wq, Wk, Wv, (const float4*)Wo,
                                      w, (ushort4*)wob, Mrb, Wvb);
    k_kp<<<1024, 256, 0, stream>>>(keys, Mrb, kk2p);
    k_w2<<<1024, 256, 0, stream>>>(query, kk2p, w);
    k_ap2<<<1024, 256, 0, stream>>>(values, Wvb, w, apb);
    k_out_mfma<<<512, 256, 0, stream>>>(apb, wob, bo, out);
}

// Round 9
// 158.599 us; speedup vs baseline: 1.2661x; 1.0159x over previous
//
#include <hip/hip_runtime.h>
#include <hip/hip_bf16.h>
#include <math.h>

// Problem constants: N=4, L=1024, D=1024, H=16, HD=64, HIST=128, SCALE=32
// Faithful-bug structure: attention[n,l,h,d] = (sum_q scores[n,h,q,l]) * v[n,l,h,d]
// => only column sums w[n,h,l] of softmax needed.
// Energy trick: E = Xq (Wq^T Wk/32) Xk^T = Xq . kk2^T with kk2 = K.(M^T).
// Round 9: 5 -> 4 dispatches. k_stage fuses: kp (with IN-BLOCK M via 8 MFMAs,
// Wq/Wk L2-resident), planar query gather qb, Wo->bf16 cast (+w zero), Wv cast.
// k_w2 A-frags now 2 contiguous 16B reads from planar qb.
// Fixed harness cost ~100-110us (256MiB ws poison visible at ~42us); kernel-side
// budget ~55us -> attacking gaps + gather.

using short8 = __attribute__((ext_vector_type(8))) short;
using f32x4  = __attribute__((ext_vector_type(4))) float;

__device__ __forceinline__ unsigned short f2bf(float x) {
    unsigned u = __float_as_uint(x);
    u += 0x7FFFu + ((u >> 16) & 1u);      // round-to-nearest-even
    return (unsigned short)(u >> 16);
}

// ---------------------------------------------------------------------------
// K0 (k_stage), grid 3088:
//  b 0..1023   : kk2p[nh][l][e] = bf16( sum_f keys[n,l,h*64+f] * M[e,f] ),
//                M computed in-block via MFMA (A=Wq^T, B=Wk^T frags from global)
//  b 1024..2047: qb[nh][l][e] = bf16(query[n,l,h*64+e])   (planar gather)
//  b 2048..3071: wob = bf16(Wo); first 256 of these also zero w
//  b 3072..3087: Wvb = bf16(Wv)
// ---------------------------------------------------------------------------
__global__ __launch_bounds__(256) void k_stage(const float* __restrict__ keys,
                                               const float* __restrict__ query,
                                               const float* __restrict__ Wq,
                                               const float* __restrict__ Wk,
                                               const float* __restrict__ Wv,
                                               const float4* __restrict__ Wo4,
                                               unsigned short* __restrict__ kk2p,
                                               unsigned short* __restrict__ qb,
                                               ushort4* __restrict__ wob4,
                                               unsigned short* __restrict__ Wvb,
                                               float* __restrict__ w) {
    __shared__ unsigned short Ml[64 * 64];    // 8 KB, M[e][f] bf16 (kp blocks)

    const int b = blockIdx.x, tid = threadIdx.x;

    if (b < 1024) {
        // ---------------- kp: kk2 = K @ M^T ----------------
        const int wv = tid >> 6, lane = tid & 63;
        const int m = lane & 15, q4 = lane >> 4, ksel = q4 * 8;

        // phase M: D[e][f] = sum_d Wq[d][e]*Wk[d][f]  (A[e][d]=Wq[d][e], B[f][d]=Wk[d][f])
        {
            short8 aM0, aM1;
#pragma unroll
            for (int j = 0; j < 8; ++j) {
                aM0[j] = (short)f2bf(Wq[(ksel + j) * 64 + wv * 16 + m]);
                aM1[j] = (short)f2bf(Wq[(32 + ksel + j) * 64 + wv * 16 + m]);
            }
#pragma unroll
            for (int fc = 0; fc < 4; ++fc) {
                short8 bM0, bM1;
#pragma unroll
                for (int j = 0; j < 8; ++j) {
                    bM0[j] = (short)f2bf(Wk[(ksel + j) * 64 + fc * 16 + m]);
                    bM1[j] = (short)f2bf(Wk[(32 + ksel + j) * 64 + fc * 16 + m]);
                }
                f32x4 a = f32x4{0.f, 0.f, 0.f, 0.f};
                a = __builtin_amdgcn_mfma_f32_16x16x32_bf16(aM0, bM0, a, 0, 0, 0);
                a = __builtin_amdgcn_mfma_f32_16x16x32_bf16(aM1, bM1, a, 0, 0, 0);
                // C layout: col f = fc*16+m, row e = wv*16 + q4*4 + r
#pragma unroll
                for (int r = 0; r < 4; ++r)
                    Ml[(wv * 16 + q4 * 4 + r) * 64 + fc * 16 + m] =
                        f2bf(a[r] * (1.0f / 32.0f));
            }
        }
        __syncthreads();

        // phase kp: rows R0..R0+63 of keys-as-(65536,64)
        const long R0 = (long)b * 64;
        const float* ka = keys + (R0 + wv * 16 + m) * 64;
        short8 af[2];
#pragma unroll
        for (int ch = 0; ch < 2; ++ch) {
            float4 x0 = *reinterpret_cast<const float4*>(ka + ch * 32 + ksel);
            float4 x1 = *reinterpret_cast<const float4*>(ka + ch * 32 + ksel + 4);
            short8 a;
            a[0] = (short)f2bf(x0.x); a[1] = (short)f2bf(x0.y);
            a[2] = (short)f2bf(x0.z); a[3] = (short)f2bf(x0.w);
            a[4] = (short)f2bf(x1.x); a[5] = (short)f2bf(x1.y);
            a[6] = (short)f2bf(x1.z); a[7] = (short)f2bf(x1.w);
            af[ch] = a;
        }

        f32x4 acc[4];
#pragma unroll
        for (int fc = 0; fc < 4; ++fc) {
            acc[fc] = f32x4{0.f, 0.f, 0.f, 0.f};
#pragma unroll
            for (int ch = 0; ch < 2; ++ch) {
                short8 bf = *reinterpret_cast<const short8*>(
                    &Ml[(fc * 16 + m) * 64 + ch * 32 + ksel]);
                acc[fc] = __builtin_amdgcn_mfma_f32_16x16x32_bf16(af[ch], bf, acc[fc], 0, 0, 0);
            }
        }

        const long rowb = R0 + wv * 16 + (lane >> 4) * 4;
#pragma unroll
        for (int reg = 0; reg < 4; ++reg) {
            long rg = rowb + reg;
            int hh = (int)(rg & 15);
            int ll = (int)((rg >> 4) & 1023);
            int nn = (int)(rg >> 14);
            unsigned short* orow = kk2p + ((size_t)((nn * 16 + hh) * 1024 + ll)) * 64;
#pragma unroll
            for (int fc = 0; fc < 4; ++fc)
                orow[fc * 16 + m] = f2bf(acc[fc][reg]);
        }
    } else if (b < 2048) {
        // ---------------- planar query gather ----------------
        const int bb = b - 1024;
        const int tile = bb & 15, nh = bb >> 4, h = nh & 15, n = nh >> 4;
        const int t0 = tile * 64;
        const float* qbase = query + ((size_t)(n * 1024 + t0)) * 1024 + h * 64;
        unsigned short* qout = qb + ((size_t)(nh * 1024 + t0)) * 64;
#pragma unroll
        for (int i = 0; i < 4; ++i) {
            int idx = tid + i * 256;          // 1024 float4s
            int r = idx >> 4, f0 = (idx & 15) * 4;
            float4 qv = *reinterpret_cast<const float4*>(qbase + (size_t)r * 1024 + f0);
            ushort4 qo; qo.x = f2bf(qv.x); qo.y = f2bf(qv.y);
            qo.z = f2bf(qv.z); qo.w = f2bf(qv.w);
            *reinterpret_cast<ushort4*>(qout + (size_t)r * 64 + f0) = qo;
        }
    } else if (b < 3072) {
        // ---------------- Wo -> bf16 (+ zero w) ----------------
        const int bb = b - 2048;
        int idx = bb * 256 + tid;             // 262144 float4s
        float4 v = Wo4[idx];
        ushort4 o; o.x = f2bf(v.x); o.y = f2bf(v.y);
        o.z = f2bf(v.z); o.w = f2bf(v.w);
        wob4[idx] = o;
        if (bb < 256) w[bb * 256 + tid] = 0.f;
    } else {
        // ---------------- Wv -> bf16 ----------------
        int idx = (b - 3072) * 256 + tid;     // 4096
        Wvb[idx] = f2bf(Wv[idx]);
    }
}

// ---------------------------------------------------------------------------
// K1 (k_w2): per (nh, 64-row tile): energy 64x192 via MFMA, banded softmax,
// column sums -> w atomics. A-frags from planar qb (2x16B contiguous/lane).
// Swizzle: nh fast -> same-nh adjacent tiles share an XCD L2.
// ---------------------------------------------------------------------------
__global__ __launch_bounds__(256) void k_w2(const unsigned short* __restrict__ qb,
                                            const unsigned short* __restrict__ kk2p,
                                            float* __restrict__ w) {
    __shared__ float wloc[192];

    const int tid  = threadIdx.x;
    const int b    = blockIdx.x;          // 1024
    const int nh   = b & 63;              // swizzle: nh fast, tile slow
    const int tile = b >> 6;
    const int t0   = tile * 64;

    if (tid < 192) wloc[tid] = 0.f;
    __syncthreads();

    const int wv = tid >> 6, lane = tid & 63;
    const int m = lane & 15, q4 = lane >> 4, ksel = q4 * 8;

    const unsigned short* qrow = qb + ((size_t)(nh * 1024 + t0 + wv * 16 + m)) * 64;
    short8 af0 = *reinterpret_cast<const short8*>(qrow + ksel);
    short8 af1 = *reinterpret_cast<const short8*>(qrow + 32 + ksel);

    const unsigned short* kb = kk2p + (size_t)nh * 1024 * 64;

    f32x4 acc[12];
#pragma unroll
    for (int ni = 0; ni < 12; ++ni) {         // FULL unroll: compile-time idx
        int l = t0 - 127 + ni * 16 + m;
        int lc = min(max(l, 0), 1023);
        const unsigned short* kp = kb + (size_t)lc * 64 + ksel;
        short8 b0 = *reinterpret_cast<const short8*>(kp);
        short8 b1 = *reinterpret_cast<const short8*>(kp + 32);
        f32x4 a = f32x4{0.f, 0.f, 0.f, 0.f};
        a = __builtin_amdgcn_mfma_f32_16x16x32_bf16(af0, b0, a, 0, 0, 0);
        a = __builtin_amdgcn_mfma_f32_16x16x32_bf16(af1, b1, a, 0, 0, 0);
        acc[ni] = a;
    }

    // banded softmax: col c = ni*16+m, local row = wv*16 + q4*4 + reg
    const int rbase = wv * 16 + q4 * 4;
    float rs[4] = {0.f, 0.f, 0.f, 0.f};
#pragma unroll
    for (int ni = 0; ni < 12; ++ni) {
        const int c = ni * 16 + m;
#pragma unroll
        for (int reg = 0; reg < 4; ++reg) {
            const int rlw = rbase + reg;
            bool valid = (c >= rlw) && (c <= rlw + 127) && (c + t0 >= 127);
            float e = valid ? __expf(acc[ni][reg]) : 0.f;
            acc[ni][reg] = e;
            rs[reg] += e;
        }
    }
#pragma unroll
    for (int reg = 0; reg < 4; ++reg) {
#pragma unroll
        for (int mm = 1; mm < 16; mm <<= 1) rs[reg] += __shfl_xor(rs[reg], mm);
        rs[reg] = 1.0f / rs[reg];             // diagonal always valid -> > 0
    }
#pragma unroll
    for (int ni = 0; ni < 12; ++ni) {
        float cs = acc[ni][0] * rs[0] + acc[ni][1] * rs[1] +
                   acc[ni][2] * rs[2] + acc[ni][3] * rs[3];
        cs += __shfl_xor(cs, 16);
        cs += __shfl_xor(cs, 32);
        if (lane < 16) atomicAdd(&wloc[ni * 16 + m], cs);
    }
    __syncthreads();

    for (int c = tid; c < 192; c += 256) {
        int l = t0 - 127 + c;
        if (l >= 0 && l < 1024)
            atomicAdd(&w[(size_t)nh * 1024 + l], wloc[c]);
    }
}

// ---------------------------------------------------------------------------
// K2: apb[row][d] = bf16( w_scale(row) * sum_e values[row][e] * Wv[d][e] )
// ---------------------------------------------------------------------------
__global__ __launch_bounds__(256) void k_ap2(const float* __restrict__ values,
                                             const unsigned short* __restrict__ Wvb,
                                             const float* __restrict__ w,
                                             unsigned short* __restrict__ apb) {
    const int tid = threadIdx.x;
    const long R0 = (long)blockIdx.x * 64;    // 1024 blocks
    const int wv = tid >> 6, lane = tid & 63;
    const int m = lane & 15, ksel = (lane >> 4) * 8;

    const float* va = values + (R0 + wv * 16 + m) * 64;
    short8 af[2];
#pragma unroll
    for (int ch = 0; ch < 2; ++ch) {
        float4 x0 = *reinterpret_cast<const float4*>(va + ch * 32 + ksel);
        float4 x1 = *reinterpret_cast<const float4*>(va + ch * 32 + ksel + 4);
        short8 a;
        a[0] = (short)f2bf(x0.x); a[1] = (short)f2bf(x0.y);
        a[2] = (short)f2bf(x0.z); a[3] = (short)f2bf(x0.w);
        a[4] = (short)f2bf(x1.x); a[5] = (short)f2bf(x1.y);
        a[6] = (short)f2bf(x1.z); a[7] = (short)f2bf(x1.w);
        af[ch] = a;
    }

    f32x4 acc[4];
#pragma unroll
    for (int dc = 0; dc < 4; ++dc) {
        acc[dc] = f32x4{0.f, 0.f, 0.f, 0.f};
#pragma unroll
        for (int ch = 0; ch < 2; ++ch) {
            short8 bf = *reinterpret_cast<const short8*>(
                Wvb + (size_t)(dc * 16 + m) * 64 + ch * 32 + ksel);
            acc[dc] = __builtin_amdgcn_mfma_f32_16x16x32_bf16(af[ch], bf, acc[dc], 0, 0, 0);
        }
    }

    const long rowb = R0 + wv * 16 + (lane >> 4) * 4;
    float wf[4];
#pragma unroll
    for (int reg = 0; reg < 4; ++reg) {
        long rg = rowb + reg;
        int hh = (int)(rg & 15);
        int ll = (int)((rg >> 4) & 1023);
        int nn = (int)(rg >> 14);
        wf[reg] = w[((size_t)(nn * 16 + hh) << 10) + ll];
    }
#pragma unroll
    for (int dc = 0; dc < 4; ++dc)
#pragma unroll
        for (int reg = 0; reg < 4; ++reg)
            apb[(size_t)(rowb + reg) * 64 + dc * 16 + m] = f2bf(acc[dc][reg] * wf[reg]);
}

// ---------------------------------------------------------------------------
// K3: out = ap (4096x1024 bf16) @ Wo^T (bf16) + bo, f32 out.
// 128x64 tiles, 512 blocks, strip-fast swizzle.
// ---------------------------------------------------------------------------
__global__ __launch_bounds__(256) void k_out_mfma(
    const unsigned short* __restrict__ apb,
    const unsigned short* __restrict__ wob,
    const float* __restrict__ bo,
    float* __restrict__ out) {
    __shared__ unsigned short As[128 * 32];   // 8 KB
    __shared__ unsigned short Bs[64 * 32];    // 4 KB

    const int tid  = threadIdx.x;
    const int wv   = tid >> 6;     // wave 0..3 -> m-rows wv*32..+31
    const int lane = tid & 63;
    const int m    = lane & 15;

    const int by = blockIdx.x & 31;   // row strip (swizzle: strip fast)
    const int bx = blockIdx.x >> 5;   // 16 col tiles (64 cols)
    const long arow0 = (long)by * 128;
    const int  bcol0 = bx * 64;

    f32x4 acc[2][4];
#pragma unroll
    for (int mi = 0; mi < 2; ++mi)
#pragma unroll
        for (int ni = 0; ni < 4; ++ni) acc[mi][ni] = f32x4{0.f, 0.f, 0.f, 0.f};

    const int r0s = tid >> 2;         // 0..63
    const int kks = (tid & 3) * 8;

    for (int kt = 0; kt < 32; ++kt) {
        const int k0 = kt * 32;
#pragma unroll
        for (int i = 0; i < 2; ++i) {
            const unsigned short* g =
                apb + (arow0 + i * 64 + r0s) * 1024 + k0 + kks;
            __builtin_amdgcn_global_load_lds(
                (const __attribute__((address_space(1))) unsigned int*)g,
                (__attribute__((address_space(3))) unsigned int*)&As[i * 2048 + wv * 512],
                16, 0, 0);
        }
        {
            const unsigned short* g =
                wob + (size_t)(bcol0 + r0s) * 1024 + k0 + kks;
            __builtin_amdgcn_global_load_lds(
                (const __attribute__((address_space(1))) unsigned int*)g,
                (__attribute__((address_space(3))) unsigned int*)&Bs[wv * 512],
                16, 0, 0);
        }
        __syncthreads();

        const int koff = (lane >> 4) * 8;
        const int rA = wv * 32 + m;
        short8 af[2], bf[4];
#pragma unroll
        for (int mi = 0; mi < 2; ++mi)
            af[mi] = *reinterpret_cast<const short8*>(&As[(rA + mi * 16) * 32 + koff]);
#pragma unroll
        for (int ni = 0; ni < 4; ++ni)
            bf[ni] = *reinterpret_cast<const short8*>(&Bs[(ni * 16 + m) * 32 + koff]);
#pragma unroll
        for (int mi = 0; mi < 2; ++mi)
#pragma unroll
            for (int ni = 0; ni < 4; ++ni)
                acc[mi][ni] = __builtin_amdgcn_mfma_f32_16x16x32_bf16(
                    af[mi], bf[ni], acc[mi][ni], 0, 0, 0);
        __syncthreads();
    }

    const int colb = bcol0 + m;
    const int rowb = (int)arow0 + wv * 32 + (lane >> 4) * 4;
#pragma unroll
    for (int ni = 0; ni < 4; ++ni) {
        const int col = colb + ni * 16;
        const float bias = bo[col];
#pragma unroll
        for (int mi = 0; mi < 2; ++mi) {
            const int row = rowb + mi * 16;
#pragma unroll
            for (int r = 0; r < 4; ++r)
                out[(size_t)(row + r) * 1024 + col] = acc[mi][ni][r] + bias;
        }
    }
}

// ---------------------------------------------------------------------------
extern "C" void kernel_launch(void* const* d_in, const int* in_sizes, int n_in,
                              void* d_out, int out_size, void* d_ws, size_t ws_size,
                              hipStream_t stream) {
    const float* values = (const float*)d_in[0];
    const float* keys   = (const float*)d_in[1];
    const float* query  = (const float*)d_in[2];
    const float* Wv     = (const float*)d_in[4];
    const float* Wk     = (const float*)d_in[5];
    const float* Wq     = (const float*)d_in[6];
    const float* Wo     = (const float*)d_in[7];
    const float* bo     = (const float*)d_in[8];
    float* out = (float*)d_out;

    // workspace layout (~26.3 MB of the 256 MiB ws; no overlays — r3 lesson):
    float* w             = (float*)d_ws;                 // 65536 f32   (256 KB)
    unsigned short* Wvb  = (unsigned short*)(w + 65536); // 4096 bf16   (8 KB)
    unsigned short* wob  = Wvb + 4096;                   // 1M bf16     (2 MB)
    unsigned short* kk2p = wob + 1024 * 1024;            // 4M bf16     (8 MB)
    unsigned short* qb   = kk2p + 64 * 1024 * 64;        // 4M bf16     (8 MB)
    unsigned short* apb  = qb + 64 * 1024 * 64;          // 4M bf16     (8 MB)

    k_stage<<<3088, 256, 0, stream>>>(keys, query, Wq, Wk, Wv, (const float4*)Wo,
                                      kk2p, qb, (ushort4*)wob, Wvb, w);
    k_w2<<<1024, 256, 0, stream>>>(qb, kk2p, w);
    k_ap2<<<1024, 256, 0, stream>>>(values, Wvb, w, apb);
    k_out_mfma<<<512, 256, 0, stream>>>(apb, wob, bo, out);
}

// Round 10
// 157.245 us; speedup vs baseline: 1.2770x; 1.0086x over previous
//
#include <hip/hip_runtime.h>
#include <hip/hip_bf16.h>
#include <math.h>

// Problem constants: N=4, L=1024, D=1024, H=16, HD=64, HIST=128, SCALE=32
// Faithful-bug structure: attention[n,l,h,d] = (sum_q scores[n,h,q,l]) * v[n,l,h,d]
// => only column sums w[n,h,l] of softmax needed.
// Energy trick: E = Xq (Wq^T Wk/32) Xk^T = Xq . kk2^T with kk2 = K.(M^T).
// Round 10: k_out BK=64 via two proven 128x32 half-buffers per operand ->
// barrier count halved (the vmcnt(0)+s_barrier drain is the stall at
// 2 blocks/CU); staging map and MFMA accumulation order unchanged
// (bit-identical output). Harness-fixed floor ~110-125us; kernel-side ~35us.

using short8 = __attribute__((ext_vector_type(8))) short;
using f32x4  = __attribute__((ext_vector_type(4))) float;

__device__ __forceinline__ unsigned short f2bf(float x) {
    unsigned u = __float_as_uint(x);
    u += 0x7FFFu + ((u >> 16) & 1u);      // round-to-nearest-even
    return (unsigned short)(u >> 16);
}

// ---------------------------------------------------------------------------
// K0 (k_stage), grid 3088:
//  b 0..1023   : kk2p[nh][l][e] = bf16( sum_f keys[n,l,h*64+f] * M[e,f] ),
//                M computed in-block via MFMA (A=Wq^T, B=Wk^T frags from global)
//  b 1024..2047: qb[nh][l][e] = bf16(query[n,l,h*64+e])   (planar gather)
//  b 2048..3071: wob = bf16(Wo); first 256 of these also zero w
//  b 3072..3087: Wvb = bf16(Wv)
// ---------------------------------------------------------------------------
__global__ __launch_bounds__(256) void k_stage(const float* __restrict__ keys,
                                               const float* __restrict__ query,
                                               const float* __restrict__ Wq,
                                               const float* __restrict__ Wk,
                                               const float* __restrict__ Wv,
                                               const float4* __restrict__ Wo4,
                                               unsigned short* __restrict__ kk2p,
                                               unsigned short* __restrict__ qb,
                                               ushort4* __restrict__ wob4,
                                               unsigned short* __restrict__ Wvb,
                                               float* __restrict__ w) {
    __shared__ unsigned short Ml[64 * 64];    // 8 KB, M[e][f] bf16 (kp blocks)

    const int b = blockIdx.x, tid = threadIdx.x;

    if (b < 1024) {
        // ---------------- kp: kk2 = K @ M^T ----------------
        const int wv = tid >> 6, lane = tid & 63;
        const int m = lane & 15, q4 = lane >> 4, ksel = q4 * 8;

        // phase M: D[e][f] = sum_d Wq[d][e]*Wk[d][f]
        {
            short8 aM0, aM1;
#pragma unroll
            for (int j = 0; j < 8; ++j) {
                aM0[j] = (short)f2bf(Wq[(ksel + j) * 64 + wv * 16 + m]);
                aM1[j] = (short)f2bf(Wq[(32 + ksel + j) * 64 + wv * 16 + m]);
            }
#pragma unroll
            for (int fc = 0; fc < 4; ++fc) {
                short8 bM0, bM1;
#pragma unroll
                for (int j = 0; j < 8; ++j) {
                    bM0[j] = (short)f2bf(Wk[(ksel + j) * 64 + fc * 16 + m]);
                    bM1[j] = (short)f2bf(Wk[(32 + ksel + j) * 64 + fc * 16 + m]);
                }
                f32x4 a = f32x4{0.f, 0.f, 0.f, 0.f};
                a = __builtin_amdgcn_mfma_f32_16x16x32_bf16(aM0, bM0, a, 0, 0, 0);
                a = __builtin_amdgcn_mfma_f32_16x16x32_bf16(aM1, bM1, a, 0, 0, 0);
#pragma unroll
                for (int r = 0; r < 4; ++r)
                    Ml[(wv * 16 + q4 * 4 + r) * 64 + fc * 16 + m] =
                        f2bf(a[r] * (1.0f / 32.0f));
            }
        }
        __syncthreads();

        // phase kp: rows R0..R0+63 of keys-as-(65536,64)
        const long R0 = (long)b * 64;
        const float* ka = keys + (R0 + wv * 16 + m) * 64;
        short8 af[2];
#pragma unroll
        for (int ch = 0; ch < 2; ++ch) {
            float4 x0 = *reinterpret_cast<const float4*>(ka + ch * 32 + ksel);
            float4 x1 = *reinterpret_cast<const float4*>(ka + ch * 32 + ksel + 4);
            short8 a;
            a[0] = (short)f2bf(x0.x); a[1] = (short)f2bf(x0.y);
            a[2] = (short)f2bf(x0.z); a[3] = (short)f2bf(x0.w);
            a[4] = (short)f2bf(x1.x); a[5] = (short)f2bf(x1.y);
            a[6] = (short)f2bf(x1.z); a[7] = (short)f2bf(x1.w);
            af[ch] = a;
        }

        f32x4 acc[4];
#pragma unroll
        for (int fc = 0; fc < 4; ++fc) {
            acc[fc] = f32x4{0.f, 0.f, 0.f, 0.f};
#pragma unroll
            for (int ch = 0; ch < 2; ++ch) {
                short8 bf = *reinterpret_cast<const short8*>(
                    &Ml[(fc * 16 + m) * 64 + ch * 32 + ksel]);
                acc[fc] = __builtin_amdgcn_mfma_f32_16x16x32_bf16(af[ch], bf, acc[fc], 0, 0, 0);
            }
        }

        const long rowb = R0 + wv * 16 + (lane >> 4) * 4;
#pragma unroll
        for (int reg = 0; reg < 4; ++reg) {
            long rg = rowb + reg;
            int hh = (int)(rg & 15);
            int ll = (int)((rg >> 4) & 1023);
            int nn = (int)(rg >> 14);
            unsigned short* orow = kk2p + ((size_t)((nn * 16 + hh) * 1024 + ll)) * 64;
#pragma unroll
            for (int fc = 0; fc < 4; ++fc)
                orow[fc * 16 + m] = f2bf(acc[fc][reg]);
        }
    } else if (b < 2048) {
        // ---------------- planar query gather ----------------
        const int bb = b - 1024;
        const int tile = bb & 15, nh = bb >> 4, h = nh & 15, n = nh >> 4;
        const int t0 = tile * 64;
        const float* qbase = query + ((size_t)(n * 1024 + t0)) * 1024 + h * 64;
        unsigned short* qout = qb + ((size_t)(nh * 1024 + t0)) * 64;
#pragma unroll
        for (int i = 0; i < 4; ++i) {
            int idx = tid + i * 256;          // 1024 float4s
            int r = idx >> 4, f0 = (idx & 15) * 4;
            float4 qv = *reinterpret_cast<const float4*>(qbase + (size_t)r * 1024 + f0);
            ushort4 qo; qo.x = f2bf(qv.x); qo.y = f2bf(qv.y);
            qo.z = f2bf(qv.z); qo.w = f2bf(qv.w);
            *reinterpret_cast<ushort4*>(qout + (size_t)r * 64 + f0) = qo;
        }
    } else if (b < 3072) {
        // ---------------- Wo -> bf16 (+ zero w) ----------------
        const int bb = b - 2048;
        int idx = bb * 256 + tid;             // 262144 float4s
        float4 v = Wo4[idx];
        ushort4 o; o.x = f2bf(v.x); o.y = f2bf(v.y);
        o.z = f2bf(v.z); o.w = f2bf(v.w);
        wob4[idx] = o;
        if (bb < 256) w[bb * 256 + tid] = 0.f;
    } else {
        // ---------------- Wv -> bf16 ----------------
        int idx = (b - 3072) * 256 + tid;     // 4096
        Wvb[idx] = f2bf(Wv[idx]);
    }
}

// ---------------------------------------------------------------------------
// K1 (k_w2): per (nh, 64-row tile): energy 64x192 via MFMA, banded softmax,
// column sums -> w atomics. A-frags from planar qb (2x16B contiguous/lane).
// ---------------------------------------------------------------------------
__global__ __launch_bounds__(256) void k_w2(const unsigned short* __restrict__ qb,
                                            const unsigned short* __restrict__ kk2p,
                                            float* __restrict__ w) {
    __shared__ float wloc[192];

    const int tid  = threadIdx.x;
    const int b    = blockIdx.x;          // 1024
    const int nh   = b & 63;              // swizzle: nh fast, tile slow
    const int tile = b >> 6;
    const int t0   = tile * 64;

    if (tid < 192) wloc[tid] = 0.f;
    __syncthreads();

    const int wv = tid >> 6, lane = tid & 63;
    const int m = lane & 15, q4 = lane >> 4, ksel = q4 * 8;

    const unsigned short* qrow = qb + ((size_t)(nh * 1024 + t0 + wv * 16 + m)) * 64;
    short8 af0 = *reinterpret_cast<const short8*>(qrow + ksel);
    short8 af1 = *reinterpret_cast<const short8*>(qrow + 32 + ksel);

    const unsigned short* kb = kk2p + (size_t)nh * 1024 * 64;

    f32x4 acc[12];
#pragma unroll
    for (int ni = 0; ni < 12; ++ni) {         // FULL unroll: compile-time idx
        int l = t0 - 127 + ni * 16 + m;
        int lc = min(max(l, 0), 1023);
        const unsigned short* kp = kb + (size_t)lc * 64 + ksel;
        short8 b0 = *reinterpret_cast<const short8*>(kp);
        short8 b1 = *reinterpret_cast<const short8*>(kp + 32);
        f32x4 a = f32x4{0.f, 0.f, 0.f, 0.f};
        a = __builtin_amdgcn_mfma_f32_16x16x32_bf16(af0, b0, a, 0, 0, 0);
        a = __builtin_amdgcn_mfma_f32_16x16x32_bf16(af1, b1, a, 0, 0, 0);
        acc[ni] = a;
    }

    // banded softmax: col c = ni*16+m, local row = wv*16 + q4*4 + reg
    const int rbase = wv * 16 + q4 * 4;
    float rs[4] = {0.f, 0.f, 0.f, 0.f};
#pragma unroll
    for (int ni = 0; ni < 12; ++ni) {
        const int c = ni * 16 + m;
#pragma unroll
        for (int reg = 0; reg < 4; ++reg) {
            const int rlw = rbase + reg;
            bool valid = (c >= rlw) && (c <= rlw + 127) && (c + t0 >= 127);
            float e = valid ? __expf(acc[ni][reg]) : 0.f;
            acc[ni][reg] = e;
            rs[reg] += e;
        }
    }
#pragma unroll
    for (int reg = 0; reg < 4; ++reg) {
#pragma unroll
        for (int mm = 1; mm < 16; mm <<= 1) rs[reg] += __shfl_xor(rs[reg], mm);
        rs[reg] = 1.0f / rs[reg];             // diagonal always valid -> > 0
    }
#pragma unroll
    for (int ni = 0; ni < 12; ++ni) {
        float cs = acc[ni][0] * rs[0] + acc[ni][1] * rs[1] +
                   acc[ni][2] * rs[2] + acc[ni][3] * rs[3];
        cs += __shfl_xor(cs, 16);
        cs += __shfl_xor(cs, 32);
        if (lane < 16) atomicAdd(&wloc[ni * 16 + m], cs);
    }
    __syncthreads();

    for (int c = tid; c < 192; c += 256) {
        int l = t0 - 127 + c;
        if (l >= 0 && l < 1024)
            atomicAdd(&w[(size_t)nh * 1024 + l], wloc[c]);
    }
}

// ---------------------------------------------------------------------------
// K2: apb[row][d] = bf16( w_scale(row) * sum_e values[row][e] * Wv[d][e] )
// ---------------------------------------------------------------------------
__global__ __launch_bounds__(256) void k_ap2(const float* __restrict__ values,
                                             const unsigned short* __restrict__ Wvb,
                                             const float* __restrict__ w,
                                             unsigned short* __restrict__ apb) {
    const int tid = threadIdx.x;
    const long R0 = (long)blockIdx.x * 64;    // 1024 blocks
    const int wv = tid >> 6, lane = tid & 63;
    const int m = lane & 15, ksel = (lane >> 4) * 8;

    const float* va = values + (R0 + wv * 16 + m) * 64;
    short8 af[2];
#pragma unroll
    for (int ch = 0; ch < 2; ++ch) {
        float4 x0 = *reinterpret_cast<const float4*>(va + ch * 32 + ksel);
        float4 x1 = *reinterpret_cast<const float4*>(va + ch * 32 + ksel + 4);
        short8 a;
        a[0] = (short)f2bf(x0.x); a[1] = (short)f2bf(x0.y);
        a[2] = (short)f2bf(x0.z); a[3] = (short)f2bf(x0.w);
        a[4] = (short)f2bf(x1.x); a[5] = (short)f2bf(x1.y);
        a[6] = (short)f2bf(x1.z); a[7] = (short)f2bf(x1.w);
        af[ch] = a;
    }

    f32x4 acc[4];
#pragma unroll
    for (int dc = 0; dc < 4; ++dc) {
        acc[dc] = f32x4{0.f, 0.f, 0.f, 0.f};
#pragma unroll
        for (int ch = 0; ch < 2; ++ch) {
            short8 bf = *reinterpret_cast<const short8*>(
                Wvb + (size_t)(dc * 16 + m) * 64 + ch * 32 + ksel);
            acc[dc] = __builtin_amdgcn_mfma_f32_16x16x32_bf16(af[ch], bf, acc[dc], 0, 0, 0);
        }
    }

    const long rowb = R0 + wv * 16 + (lane >> 4) * 4;
    float wf[4];
#pragma unroll
    for (int reg = 0; reg < 4; ++reg) {
        long rg = rowb + reg;
        int hh = (int)(rg & 15);
        int ll = (int)((rg >> 4) & 1023);
        int nn = (int)(rg >> 14);
        wf[reg] = w[((size_t)(nn * 16 + hh) << 10) + ll];
    }
#pragma unroll
    for (int dc = 0; dc < 4; ++dc)
#pragma unroll
        for (int reg = 0; reg < 4; ++reg)
            apb[(size_t)(rowb + reg) * 64 + dc * 16 + m] = f2bf(acc[dc][reg] * wf[reg]);
}

// ---------------------------------------------------------------------------
// K3: out = ap (4096x1024 bf16) @ Wo^T (bf16) + bo, f32 out.
// 128x64 tiles, 512 blocks, strip-fast swizzle. BK=64 via two 128x32
// half-buffers per operand: staging map identical to the proven BK=32 one,
// but only 16 K-iterations -> barrier count halved. MFMA k-order preserved
// (bit-identical to BK=32 version).
// ---------------------------------------------------------------------------
__global__ __launch_bounds__(256) void k_out_mfma(
    const unsigned short* __restrict__ apb,
    const unsigned short* __restrict__ wob,
    const float* __restrict__ bo,
    float* __restrict__ out) {
    __shared__ unsigned short As[2][128 * 32];   // 2 x 8 KB
    __shared__ unsigned short Bs[2][64 * 32];    // 2 x 4 KB

    const int tid  = threadIdx.x;
    const int wv   = tid >> 6;     // wave 0..3 -> m-rows wv*32..+31
    const int lane = tid & 63;
    const int m    = lane & 15;

    const int by = blockIdx.x & 31;   // row strip (swizzle: strip fast)
    const int bx = blockIdx.x >> 5;   // 16 col tiles (64 cols)
    const long arow0 = (long)by * 128;
    const int  bcol0 = bx * 64;

    f32x4 acc[2][4];
#pragma unroll
    for (int mi = 0; mi < 2; ++mi)
#pragma unroll
        for (int ni = 0; ni < 4; ++ni) acc[mi][ni] = f32x4{0.f, 0.f, 0.f, 0.f};

    const int r0s = tid >> 2;         // 0..63
    const int kks = (tid & 3) * 8;

    for (int kt = 0; kt < 16; ++kt) {
        const int k0 = kt * 64;
#pragma unroll
        for (int hh = 0; hh < 2; ++hh) {
            const int kh = k0 + hh * 32;
#pragma unroll
            for (int i = 0; i < 2; ++i) {
                const unsigned short* g =
                    apb + (arow0 + i * 64 + r0s) * 1024 + kh + kks;
                __builtin_amdgcn_global_load_lds(
                    (const __attribute__((address_space(1))) unsigned int*)g,
                    (__attribute__((address_space(3))) unsigned int*)&As[hh][i * 2048 + wv * 512],
                    16, 0, 0);
            }
            {
                const unsigned short* g =
                    wob + (size_t)(bcol0 + r0s) * 1024 + kh + kks;
                __builtin_amdgcn_global_load_lds(
                    (const __attribute__((address_space(1))) unsigned int*)g,
                    (__attribute__((address_space(3))) unsigned int*)&Bs[hh][wv * 512],
                    16, 0, 0);
            }
        }
        __syncthreads();

        const int koff = (lane >> 4) * 8;
        const int rA = wv * 32 + m;
        short8 af[2][2], bf[4][2];
#pragma unroll
        for (int hh = 0; hh < 2; ++hh) {
#pragma unroll
            for (int mi = 0; mi < 2; ++mi)
                af[mi][hh] = *reinterpret_cast<const short8*>(
                    &As[hh][(rA + mi * 16) * 32 + koff]);
#pragma unroll
            for (int ni = 0; ni < 4; ++ni)
                bf[ni][hh] = *reinterpret_cast<const short8*>(
                    &Bs[hh][(ni * 16 + m) * 32 + koff]);
        }
#pragma unroll
        for (int mi = 0; mi < 2; ++mi)
#pragma unroll
            for (int ni = 0; ni < 4; ++ni) {
                acc[mi][ni] = __builtin_amdgcn_mfma_f32_16x16x32_bf16(
                    af[mi][0], bf[ni][0], acc[mi][ni], 0, 0, 0);
                acc[mi][ni] = __builtin_amdgcn_mfma_f32_16x16x32_bf16(
                    af[mi][1], bf[ni][1], acc[mi][ni], 0, 0, 0);
            }
        __syncthreads();
    }

    const int colb = bcol0 + m;
    const int rowb = (int)arow0 + wv * 32 + (lane >> 4) * 4;
#pragma unroll
    for (int ni = 0; ni < 4; ++ni) {
        const int col = colb + ni * 16;
        const float bias = bo[col];
#pragma unroll
        for (int mi = 0; mi < 2; ++mi) {
            const int row = rowb + mi * 16;
#pragma unroll
            for (int r = 0; r < 4; ++r)
                out[(size_t)(row + r) * 1024 + col] = acc[mi][ni][r] + bias;
        }
    }
}

// ---------------------------------------------------------------------------
extern "C" void kernel_launch(void* const* d_in, const int* in_sizes, int n_in,
                              void* d_out, int out_size, void* d_ws, size_t ws_size,
                              hipStream_t stream) {
    const float* values = (const float*)d_in[0];
    const float* keys   = (const float*)d_in[1];
    const float* query  = (const float*)d_in[2];
    const float* Wv     = (const float*)d_in[4];
    const float* Wk     = (const float*)d_in[5];
    const float* Wq     = (const float*)d_in[6];
    const float* Wo     = (const float*)d_in[7];
    const float* bo     = (const float*)d_in[8];
    float* out = (float*)d_out;

    // workspace layout (~26.3 MB of the 256 MiB ws; no overlays — r3 lesson):
    float* w             = (float*)d_ws;                 // 65536 f32   (256 KB)
    unsigned short* Wvb  = (unsigned short*)(w + 65536); // 4096 bf16   (8 KB)
    unsigned short* wob  = Wvb + 4096;                   // 1M bf16     (2 MB)
    unsigned short* kk2p = wob + 1024 * 1024;            // 4M bf16     (8 MB)
    unsigned short* qb   = kk2p + 64 * 1024 * 64;        // 4M bf16     (8 MB)
    unsigned short* apb  = qb + 64 * 1024 * 64;          // 4M bf16     (8 MB)

    k_stage<<<3088, 256, 0, stream>>>(keys, query, Wq, Wk, Wv, (const float4*)Wo,
                                      kk2p, qb, (ushort4*)wob, Wvb, w);
    k_w2<<<1024, 256, 0, stream>>>(qb, kk2p, w);
    k_ap2<<<1024, 256, 0, stream>>>(values, Wvb, w, apb);
    k_out_mfma<<<512, 256, 0, stream>>>(apb, wob, bo, out);
}